// Round 14
// baseline (172.253 us; speedup 1.0000x reference)
//
#include <hip/hip_runtime.h>
#include <hip/hip_bf16.h>

#define KD 128   // KEY_DIM
#define VD 64    // VALUE_DIM
#define NA 256   // N_ACTIONS
#define NB 32    // B
#define LL 2048  // L

typedef __attribute__((ext_vector_type(8))) short bf16x8;
typedef __attribute__((ext_vector_type(4))) float f32x4;
typedef __attribute__((ext_vector_type(8))) unsigned short u16x8;
typedef __attribute__((ext_vector_type(4))) unsigned short u16x4;

static __device__ __forceinline__ unsigned short f2bf(float x) {
  __hip_bfloat16 h = __float2bfloat16(x);
  unsigned short u;
  __builtin_memcpy(&u, &h, 2);
  return u;
}

static __device__ __forceinline__ void stage16(const void* gsrc, void* ldst) {
  __builtin_amdgcn_global_load_lds(
      (const __attribute__((address_space(1))) void*)gsrc,
      (__attribute__((address_space(3))) void*)ldst, 16, 0, 0);
}

// ---------------------------------------------------------------
// K1: W2[n][a] = sum_k W[n][k][a]   (128 x 256 fp32)
// ---------------------------------------------------------------
__global__ __launch_bounds__(256) void fold_w(const float* __restrict__ W,
                                              float* __restrict__ W2) {
  const int idx = blockIdx.x * 256 + threadIdx.x;   // n*256 + a
  const int n = idx >> 8, a = idx & 255;
  const float* p = W + (long)n * (VD * NA) + a;
  float s = 0.f;
  #pragma unroll
  for (int k = 0; k < VD; ++k) s += p[k * NA];
  W2[idx] = s;
}

// ---------------------------------------------------------------
// K2: Tt[b][d][n] = sum_a W2[n][a] * V[b][a][d]   (bf16 out, transposed)
// ---------------------------------------------------------------
__global__ __launch_bounds__(128) void compute_t(const float* __restrict__ W2,
                                                 const float* __restrict__ V,
                                                 unsigned short* __restrict__ Tt) {
  const int n = threadIdx.x;
  const int d0 = blockIdx.x * 8;
  const int b = blockIdx.y;
  const float* vb = V + (long)b * NA * KD + d0;
  const float* w2p = W2 + n * NA;
  float acc[8] = {0.f, 0.f, 0.f, 0.f, 0.f, 0.f, 0.f, 0.f};
  for (int a = 0; a < NA; a += 4) {
    const float4 w = *(const float4*)(w2p + a);
    const float wq[4] = {w.x, w.y, w.z, w.w};
    #pragma unroll
    for (int q = 0; q < 4; ++q) {
      const float* vr = vb + (long)(a + q) * KD;
      #pragma unroll
      for (int j = 0; j < 8; ++j) acc[j] += wq[q] * vr[j];
    }
  }
  #pragma unroll
  for (int j = 0; j < 8; ++j)
    Tt[((long)b * KD + d0 + j) * KD + n] = f2bf(acc[j]);
}

// ---------------------------------------------------------------
// K3: key fp32 -> bf16, 8 elements/thread
// ---------------------------------------------------------------
__global__ __launch_bounds__(256) void cvt_key(const float* __restrict__ in,
                                               unsigned short* __restrict__ out) {
  const long i = ((long)blockIdx.x * 256 + threadIdx.x) * 8;
  const float4 f0 = *(const float4*)(in + i);
  const float4 f1 = *(const float4*)(in + i + 4);
  u16x8 r;
  r[0] = f2bf(f0.x); r[1] = f2bf(f0.y); r[2] = f2bf(f0.z); r[3] = f2bf(f0.w);
  r[4] = f2bf(f1.x); r[5] = f2bf(f1.y); r[6] = f2bf(f1.z); r[7] = f2bf(f1.w);
  *(u16x8*)(out + i) = r;
}

// ---------------------------------------------------------------
// K4: FUSED q GEMM, 2 blocks/CU. Block (b, nt of 16), 512 blocks,
// 256 threads (4 waves, 2Mx2N), tile BM=64 x BN=128 per gen, 32 gens.
// LDS 64 KB/block (B panel 32 KB + A dbuf 2x16 KB) -> 2 co-resident
// blocks absorb each other's barrier/vmcnt stalls (the round-13
// residual: 1 block/CU went idle at every per-gen sync).
// Prologue: stage Tt[b] (32 KB -> A0|A1) + keyB chunk rows
//   [nt*128,+128) (32 KB -> ldsB); panel = chunk @ Tt^T in regs
//   (pacc[2][8], 64 MFMA/wave); swizzled ds_write panel -> ldsB.
// Main loop: round-10 schedule: stage A(t+1) -> compute -> 8 stores
//   -> vmcnt(8) [queue: S(t-1)8 | L(t+1)4 | S(t)8; drain-to-8 retires
//   S(t-1)+L(t+1), keeps S(t) in flight] -> s_barrier.
// ---------------------------------------------------------------
__global__ __launch_bounds__(256, 2) void gemm_q(const unsigned short* __restrict__ A,
                                                 const unsigned short* __restrict__ Tt,
                                                 float* __restrict__ C) {
  __shared__ unsigned short ldsB[16384];   // 32 KB: chunk, then B panel
  __shared__ unsigned short ldsA0[8192];   // 16 KB: Tt low,  then A ping
  __shared__ unsigned short ldsA1[8192];   // 16 KB: Tt high, then A pong

  // 512 blocks: xcd = bid % 8 owns 64 logical = 4 whole batches
  const int lg = (blockIdx.x & 7) * 64 + (blockIdx.x >> 3);
  const int nt = lg & 15;
  const int b = lg >> 4;

  const int tid = threadIdx.x;
  const int lane = tid & 63, w = tid >> 6;     // 4 waves
  const int l15 = lane & 15, lhi = lane >> 4;
  const int wrM = w >> 1;                      // 0..1 : 32-row half (main loop)
  const int wcN = w & 1;                       // 0..1 : 64-col half (main loop)

  const unsigned short* gAb = A + (long)b * LL * KD;            // keyB[b]
  const unsigned short* gT = Tt + (long)b * KD * KD;            // Tt[b]
  const unsigned short* gChunk = gAb + (long)nt * 128 * KD;     // B-source rows

  // ---- prologue 1: stage Tt (32 KB -> A0|A1) + chunk (32 KB -> ldsB) ----
  #pragma unroll
  for (int i = 0; i < 8; ++i) {
    const int addr = i * 4096 + tid * 16;
    const int row = addr >> 8;
    const int src = addr ^ ((row & 7) << 4);
    char* dst = (addr < 16384) ? ((char*)ldsA0 + addr) : ((char*)ldsA1 + addr - 16384);
    stage16((const char*)gT + src, dst);
    stage16((const char*)gChunk + src, (char*)ldsB + addr);
  }
  asm volatile("s_waitcnt vmcnt(0)" ::: "memory");
  __builtin_amdgcn_s_barrier();
  __builtin_amdgcn_sched_barrier(0);

  // ---- prologue 2: panel = chunk (128x128) @ Tt^T (128x128) in regs ----
  // wave w owns chunk rows [w*32, +32): pacc[rf 0..1][df 0..7].
  f32x4 pacc[2][8];
  #pragma unroll
  for (int i = 0; i < 2; ++i)
    #pragma unroll
    for (int j = 0; j < 8; ++j) pacc[i][j] = f32x4{0.f, 0.f, 0.f, 0.f};

  #pragma unroll
  for (int ks = 0; ks < 4; ++ks) {
    const int kb = (ks * 32 + lhi * 8) * 2;
    bf16x8 av[2], bv[8];
    #pragma unroll
    for (int rf = 0; rf < 2; ++rf) {
      const int row = w * 32 + rf * 16 + l15;          // 0..127 in chunk
      const int byte = (row * 256 + kb) ^ ((row & 7) << 4);
      av[rf] = *(const bf16x8*)((const char*)ldsB + byte);
    }
    #pragma unroll
    for (int df = 0; df < 8; ++df) {
      const int row = df * 16 + l15;                   // Tt row = d, 0..127
      const int byte = (row * 256 + kb) ^ ((row & 7) << 4);
      bv[df] = (byte < 16384)
          ? *(const bf16x8*)((const char*)ldsA0 + byte)
          : *(const bf16x8*)((const char*)ldsA1 + (byte - 16384));
    }
    #pragma unroll
    for (int rf = 0; rf < 2; ++rf)
      #pragma unroll
      for (int df = 0; df < 8; ++df)
        pacc[rf][df] = __builtin_amdgcn_mfma_f32_16x16x32_bf16(bv[df], av[rf],
                                                               pacc[rf][df], 0, 0, 0);
  }
  asm volatile("s_waitcnt lgkmcnt(0)" ::: "memory");
  __builtin_amdgcn_sched_barrier(0);
  __builtin_amdgcn_s_barrier();
  __builtin_amdgcn_sched_barrier(0);

  // ---- prologue 3: issue A(0) stage FIRST, then ds_write panel -> ldsB ----
  #pragma unroll
  for (int i = 0; i < 4; ++i) {
    const int addr = i * 4096 + tid * 16;    // A strip 16 KB (64 rows)
    const int row = addr >> 8;
    const int src = addr ^ ((row & 7) << 4);
    stage16((const char*)gAb + src, (char*)ldsA0 + addr);
  }
  __builtin_amdgcn_sched_barrier(0);
  // panel frag: lane&15 = chunk-row (within 16), lhi*4+reg = d col.
  #pragma unroll
  for (int rf = 0; rf < 2; ++rf)
    #pragma unroll
    for (int df = 0; df < 8; ++df) {
      const int row = w * 32 + rf * 16 + l15;          // 0..127
      const int d = df * 16 + lhi * 4;
      u16x4 v;
      #pragma unroll
      for (int i = 0; i < 4; ++i) v[i] = f2bf(pacc[rf][df][i]);
      const int byte = (row * 256 + d * 2) ^ ((row & 7) << 4);
      *(u16x4*)((char*)ldsB + byte) = v;
    }
  asm volatile("s_waitcnt vmcnt(0) lgkmcnt(0)" ::: "memory");
  __builtin_amdgcn_sched_barrier(0);
  __builtin_amdgcn_s_barrier();
  __builtin_amdgcn_sched_barrier(0);

  const int col0 = nt * 128 + wcN * 64;

  // ---- main loop: 32 gens of 64x128, round-10 schedule ----
  auto gen = [&](int mt, const unsigned short* abuf, unsigned short* nbuf) {
    // issue next-gen A(mt+1) stage FIRST (oldest in VM queue)
    if (mt < 31) {
      const char* gA = (const char*)(gAb + (long)(mt + 1) * 64 * KD);
      #pragma unroll
      for (int i = 0; i < 4; ++i) {
        const int addr = i * 4096 + tid * 16;
        const int row = addr >> 8;
        const int src = addr ^ ((row & 7) << 4);
        stage16(gA + src, (char*)nbuf + addr);
      }
    }
    __builtin_amdgcn_sched_barrier(0);

    // compute 64x128 from abuf + ldsB
    f32x4 acc[2][4];
    #pragma unroll
    for (int i = 0; i < 2; ++i)
      #pragma unroll
      for (int j = 0; j < 4; ++j) acc[i][j] = f32x4{0.f, 0.f, 0.f, 0.f};

    #pragma unroll
    for (int ks = 0; ks < 4; ++ks) {
      const int kb = (ks * 32 + lhi * 8) * 2;
      bf16x8 av[2], bv[4];
      #pragma unroll
      for (int mf = 0; mf < 2; ++mf) {
        const int row = wrM * 32 + mf * 16 + l15;      // 0..63
        const int byte = (row * 256 + kb) ^ ((row & 7) << 4);
        av[mf] = *(const bf16x8*)((const char*)abuf + byte);
      }
      #pragma unroll
      for (int nf = 0; nf < 4; ++nf) {
        const int row = wcN * 64 + nf * 16 + l15;      // 0..127
        const int byte = (row * 256 + kb) ^ ((row & 7) << 4);
        bv[nf] = *(const bf16x8*)((const char*)ldsB + byte);
      }
      // swapped operands: lane&15 = out row, (lane>>4)*4+reg = out col
      #pragma unroll
      for (int mf = 0; mf < 2; ++mf)
        #pragma unroll
        for (int nf = 0; nf < 4; ++nf)
          acc[mf][nf] = __builtin_amdgcn_mfma_f32_16x16x32_bf16(bv[nf], av[mf],
                                                                acc[mf][nf], 0, 0, 0);
    }

    // 8 cached dwordx4 stores (fire and forget)
    const long row0 = (long)b * LL + mt * 64 + wrM * 32;
    #pragma unroll
    for (int mf = 0; mf < 2; ++mf)
      #pragma unroll
      for (int nf = 0; nf < 4; ++nf) {
        const long r = row0 + mf * 16 + l15;
        const int c = col0 + nf * 16 + lhi * 4;
        *(f32x4*)(C + r * LL + c) = acc[mf][nf];
      }

    // end-of-gen: drain S(mt-1)+L(mt+1), keep S(mt) in flight
    if (mt < 31) {
      asm volatile("s_waitcnt vmcnt(8)" ::: "memory");
      __builtin_amdgcn_sched_barrier(0);
      __builtin_amdgcn_s_barrier();
      __builtin_amdgcn_sched_barrier(0);
    }
  };

  #pragma unroll 1
  for (int mt2 = 0; mt2 < 16; ++mt2) {
    gen(2 * mt2, ldsA0, ldsA1);
    gen(2 * mt2 + 1, ldsA1, ldsA0);
  }
}

// ---------------------------------------------------------------
// launch
// ---------------------------------------------------------------
extern "C" void kernel_launch(void* const* d_in, const int* in_sizes, int n_in,
                              void* d_out, int out_size, void* d_ws, size_t ws_size,
                              hipStream_t stream) {
  const float* key = (const float*)d_in[0];  // (32, 2048, 128)
  const float* val = (const float*)d_in[1];  // (32, 256, 128)
  const float* wts = (const float*)d_in[2];  // (128, 64, 256)
  float* out = (float*)d_out;                // (32, 2048, 2048) fp32

  // workspace layout
  char* ws = (char*)d_ws;
  float* W2 = (float*)ws;                                        // 128 KiB
  unsigned short* Tt = (unsigned short*)(ws + 131072);           // 1 MiB
  unsigned short* keyB = (unsigned short*)(ws + 131072 + 1048576);  // 16 MiB

  fold_w<<<128, 256, 0, stream>>>(wts, W2);
  cvt_key<<<4096, 256, 0, stream>>>(key, keyB);
  compute_t<<<dim3(16, NB), 128, 0, stream>>>(W2, val, Tt);
  gemm_q<<<16 * NB, 256, 0, stream>>>(keyB, Tt, out);
}

// Round 15
// 157.888 us; speedup vs baseline: 1.0910x; 1.0910x over previous
//
#include <hip/hip_runtime.h>
#include <hip/hip_bf16.h>

#define KD 128   // KEY_DIM
#define VD 64    // VALUE_DIM
#define NA 256   // N_ACTIONS
#define NB 32    // B
#define LL 2048  // L

typedef __attribute__((ext_vector_type(8))) short bf16x8;
typedef __attribute__((ext_vector_type(4))) float f32x4;
typedef __attribute__((ext_vector_type(8))) unsigned short u16x8;
typedef __attribute__((ext_vector_type(4))) unsigned short u16x4;

static __device__ __forceinline__ unsigned short f2bf(float x) {
  __hip_bfloat16 h = __float2bfloat16(x);
  unsigned short u;
  __builtin_memcpy(&u, &h, 2);
  return u;
}

static __device__ __forceinline__ void stage16(const void* gsrc, void* ldst) {
  __builtin_amdgcn_global_load_lds(
      (const __attribute__((address_space(1))) void*)gsrc,
      (__attribute__((address_space(3))) void*)ldst, 16, 0, 0);
}

static __device__ __forceinline__ u16x8 cvt8(const float4 f0, const float4 f1) {
  u16x8 v;
  v[0] = f2bf(f0.x); v[1] = f2bf(f0.y); v[2] = f2bf(f0.z); v[3] = f2bf(f0.w);
  v[4] = f2bf(f1.x); v[5] = f2bf(f1.y); v[6] = f2bf(f1.z); v[7] = f2bf(f1.w);
  return v;
}

// ---------------------------------------------------------------
// K1: W2[n][a] = sum_k W[n][k][a]   (128 x 256 fp32)
// ---------------------------------------------------------------
__global__ __launch_bounds__(256) void fold_w(const float* __restrict__ W,
                                              float* __restrict__ W2) {
  const int idx = blockIdx.x * 256 + threadIdx.x;   // n*256 + a
  const int n = idx >> 8, a = idx & 255;
  const float* p = W + (long)n * (VD * NA) + a;
  float s = 0.f;
  #pragma unroll
  for (int k = 0; k < VD; ++k) s += p[k * NA];
  W2[idx] = s;
}

// ---------------------------------------------------------------
// K2: Tt[b][d][n] = sum_a W2[n][a] * V[b][a][d]   (bf16 out, transposed)
// ---------------------------------------------------------------
__global__ __launch_bounds__(128) void compute_t(const float* __restrict__ W2,
                                                 const float* __restrict__ V,
                                                 unsigned short* __restrict__ Tt) {
  const int n = threadIdx.x;
  const int d0 = blockIdx.x * 8;
  const int b = blockIdx.y;
  const float* vb = V + (long)b * NA * KD + d0;
  const float* w2p = W2 + n * NA;
  float acc[8] = {0.f, 0.f, 0.f, 0.f, 0.f, 0.f, 0.f, 0.f};
  for (int a = 0; a < NA; a += 4) {
    const float4 w = *(const float4*)(w2p + a);
    const float wq[4] = {w.x, w.y, w.z, w.w};
    #pragma unroll
    for (int q = 0; q < 4; ++q) {
      const float* vr = vb + (long)(a + q) * KD;
      #pragma unroll
      for (int j = 0; j < 8; ++j) acc[j] += wq[q] * vr[j];
    }
  }
  #pragma unroll
  for (int j = 0; j < 8; ++j)
    Tt[((long)b * KD + d0 + j) * KD + n] = f2bf(acc[j]);
}

// ---------------------------------------------------------------
// K3: FULLY-FUSED q GEMM. Block (b, nt), 256 blocks (1/CU), 512 thr.
// Reads fp32 key DIRECTLY (cvt_key + keyB eliminated):
//  - prologue: reg-stage chunk (256x128 fp32 -> bf16 -> swizzled
//    ds_write A0|A1) + stage16 Tt (32 KB -> ldsB low); panel =
//    chunk @ Tt^T in regs (64 MFMA/wave); issue A(0) fp32 loads;
//    ds_write panel -> ldsB; cvt+write A(0) -> ldsA0.
//  - main loop (round-10/13 schedule, constants re-derived):
//    per gen: issue 8 fp32 tile loads (regs) -> compute from abuf +
//    ldsB -> 16 stores -> vmcnt(16) [queue L8|S16: retires S(t-1)16
//    + L8, leaves S(t)16 in flight] -> cvt + swizzled ds_write nbuf
//    -> lgkmcnt(0) -> s_barrier.
// key (33.5 MB) is L3-resident after first touch; bf16 A-tiles never
// exist in HBM. LDS: ldsB 64 KB + A0/A1 2x32 KB = 128 KB.
// ---------------------------------------------------------------
__global__ __launch_bounds__(512, 2) void gemm_q(const float* __restrict__ key,
                                                 const unsigned short* __restrict__ Tt,
                                                 float* __restrict__ C) {
  __shared__ unsigned short ldsB[32768];   // Tt low 32 KB, then B panel 64 KB
  __shared__ unsigned short ldsA0[16384];  // chunk low  / A ping (32 KB)
  __shared__ unsigned short ldsA1[16384];  // chunk high / A pong (32 KB)

  // 256 blocks: xcd = bid % 8 owns 32 logical = 4 whole batches
  const int lg = (blockIdx.x & 7) * 32 + (blockIdx.x >> 3);
  const int nt = lg & 7;
  const int b = lg >> 3;

  const int tid = threadIdx.x;
  const int lane = tid & 63, w = tid >> 6;     // 8 waves
  const int l15 = lane & 15, lhi = lane >> 4;
  const int wrM = w >> 2;                      // 0..1 : 64-row half (main loop)
  const int wcN = w & 3;                       // 0..3 : 64-col block (main loop)

  const float* gK = key + (long)b * LL * KD;                    // key[b] fp32
  const unsigned short* gT = Tt + (long)b * KD * KD;            // Tt[b]
  const float* gChunk = gK + (long)nt * 256 * KD;               // B-source rows

  // ---- prologue 1: Tt -> ldsB low (DMA); chunk fp32 -> regs ----
  #pragma unroll
  for (int i = 0; i < 4; ++i) {
    const int addr = i * 8192 + tid * 16;
    const int row = addr >> 8;
    const int src = addr ^ ((row & 7) << 4);
    stage16((const char*)gT + src, (char*)ldsB + addr);
  }
  {
    float4 cf[8][2];
    #pragma unroll
    for (int it = 0; it < 8; ++it) {
      const int idx = it * 512 + tid;          // 4096 groups (256 rows x 16)
      const int row = idx >> 4, c8 = idx & 15;
      const float* p = gChunk + (long)row * KD + c8 * 8;
      cf[it][0] = *(const float4*)p;
      cf[it][1] = *(const float4*)(p + 4);
    }
    #pragma unroll
    for (int it = 0; it < 8; ++it) {
      const int idx = it * 512 + tid;
      const int row = idx >> 4, c8 = idx & 15;
      const u16x8 v = cvt8(cf[it][0], cf[it][1]);
      const int byte = (row * 256 + c8 * 16) ^ ((row & 7) << 4);
      if (byte < 32768) *(u16x8*)((char*)ldsA0 + byte) = v;
      else              *(u16x8*)((char*)ldsA1 + byte - 32768) = v;
    }
  }
  asm volatile("s_waitcnt vmcnt(0) lgkmcnt(0)" ::: "memory");
  __builtin_amdgcn_sched_barrier(0);
  __builtin_amdgcn_s_barrier();
  __builtin_amdgcn_sched_barrier(0);

  // ---- prologue 2: panel = chunk (256x128) @ Tt^T (128x128) in regs ----
  // wave w owns chunk rows [w*32, +32): pacc[rf 0..1][df 0..7].
  f32x4 pacc[2][8];
  #pragma unroll
  for (int i = 0; i < 2; ++i)
    #pragma unroll
    for (int j = 0; j < 8; ++j) pacc[i][j] = f32x4{0.f, 0.f, 0.f, 0.f};

  #pragma unroll
  for (int ks = 0; ks < 4; ++ks) {
    const int kb = (ks * 32 + lhi * 8) * 2;
    bf16x8 av[2], bv[8];
    #pragma unroll
    for (int rf = 0; rf < 2; ++rf) {
      const int row = w * 32 + rf * 16 + l15;          // 0..255 in chunk
      const int byte = (row * 256 + kb) ^ ((row & 7) << 4);
      av[rf] = (row < 128)
          ? *(const bf16x8*)((const char*)ldsA0 + byte)
          : *(const bf16x8*)((const char*)ldsA1 + (byte - 32768));
    }
    #pragma unroll
    for (int df = 0; df < 8; ++df) {
      const int row = df * 16 + l15;                   // Tt row = d
      const int byte = (row * 256 + kb) ^ ((row & 7) << 4);
      bv[df] = *(const bf16x8*)((const char*)ldsB + byte);
    }
    #pragma unroll
    for (int rf = 0; rf < 2; ++rf)
      #pragma unroll
      for (int df = 0; df < 8; ++df)
        pacc[rf][df] = __builtin_amdgcn_mfma_f32_16x16x32_bf16(bv[df], av[rf],
                                                               pacc[rf][df], 0, 0, 0);
  }
  asm volatile("s_waitcnt lgkmcnt(0)" ::: "memory");
  __builtin_amdgcn_sched_barrier(0);
  __builtin_amdgcn_s_barrier();
  __builtin_amdgcn_sched_barrier(0);

  // ---- prologue 3: issue A(0) fp32 loads; ds_write panel; cvt A(0) ----
  float4 af[4][2];
  #pragma unroll
  for (int it = 0; it < 4; ++it) {
    const int idx = it * 512 + tid;            // 2048 groups (128 rows x 16)
    const int row = idx >> 4, c8 = idx & 15;
    const float* p = gK + (long)row * KD + c8 * 8;   // tile 0
    af[it][0] = *(const float4*)p;
    af[it][1] = *(const float4*)(p + 4);
  }
  __builtin_amdgcn_sched_barrier(0);
  // panel frag: lane&15 = chunk-row (within 16), lhi*4+reg = d col.
  #pragma unroll
  for (int rf = 0; rf < 2; ++rf)
    #pragma unroll
    for (int df = 0; df < 8; ++df) {
      const int row = w * 32 + rf * 16 + l15;          // 0..255
      const int d = df * 16 + lhi * 4;
      u16x4 v;
      #pragma unroll
      for (int i = 0; i < 4; ++i) v[i] = f2bf(pacc[rf][df][i]);
      const int byte = (row * 256 + d * 2) ^ ((row & 7) << 4);
      *(u16x4*)((char*)ldsB + byte) = v;
    }
  asm volatile("s_waitcnt vmcnt(0)" ::: "memory");
  __builtin_amdgcn_sched_barrier(0);
  #pragma unroll
  for (int it = 0; it < 4; ++it) {
    const int idx = it * 512 + tid;
    const int row = idx >> 4, c8 = idx & 15;
    const u16x8 v = cvt8(af[it][0], af[it][1]);
    const int byte = (row * 256 + c8 * 16) ^ ((row & 7) << 4);
    *(u16x8*)((char*)ldsA0 + byte) = v;
  }
  asm volatile("s_waitcnt lgkmcnt(0)" ::: "memory");
  __builtin_amdgcn_sched_barrier(0);
  __builtin_amdgcn_s_barrier();
  __builtin_amdgcn_sched_barrier(0);

  const int col0 = nt * 256 + wcN * 64;

  // ---- main loop: round-13 schedule, reg-staged fp32 A tiles ----
  auto gen = [&](int mt, const unsigned short* abuf, unsigned short* nbuf) {
    // 1. issue A(mt+1) fp32 loads FIRST (oldest in VM queue)
    float4 nf4[4][2];
    if (mt < 15) {
      const float* gA = gK + (long)(mt + 1) * 128 * KD;
      #pragma unroll
      for (int it = 0; it < 4; ++it) {
        const int idx = it * 512 + tid;
        const int row = idx >> 4, c8 = idx & 15;
        const float* p = gA + (long)row * KD + c8 * 8;
        nf4[it][0] = *(const float4*)p;
        nf4[it][1] = *(const float4*)(p + 4);
      }
    }
    __builtin_amdgcn_sched_barrier(0);

    // 2. compute 128x256 from abuf + ldsB
    f32x4 acc[4][4];
    #pragma unroll
    for (int i = 0; i < 4; ++i)
      #pragma unroll
      for (int j = 0; j < 4; ++j) acc[i][j] = f32x4{0.f, 0.f, 0.f, 0.f};

    #pragma unroll
    for (int ks = 0; ks < 4; ++ks) {
      const int kb = (ks * 32 + lhi * 8) * 2;
      bf16x8 av[4], bv[4];
      #pragma unroll
      for (int mf = 0; mf < 4; ++mf) {
        const int row = wrM * 64 + mf * 16 + l15;
        const int byte = (row * 256 + kb) ^ ((row & 7) << 4);
        av[mf] = *(const bf16x8*)((const char*)abuf + byte);
      }
      #pragma unroll
      for (int nf = 0; nf < 4; ++nf) {
        const int row = wcN * 64 + nf * 16 + l15;
        const int byte = (row * 256 + kb) ^ ((row & 7) << 4);
        bv[nf] = *(const bf16x8*)((const char*)ldsB + byte);
      }
      // swapped operands: lane&15 = out row, (lane>>4)*4+reg = out col
      #pragma unroll
      for (int mf = 0; mf < 4; ++mf)
        #pragma unroll
        for (int nf = 0; nf < 4; ++nf)
          acc[mf][nf] = __builtin_amdgcn_mfma_f32_16x16x32_bf16(bv[nf], av[mf],
                                                                acc[mf][nf], 0, 0, 0);
    }

    // 3. 16 cached dwordx4 stores (fire and forget)
    const long row0 = (long)b * LL + mt * 128 + wrM * 64;
    #pragma unroll
    for (int mf = 0; mf < 4; ++mf)
      #pragma unroll
      for (int nf = 0; nf < 4; ++nf) {
        const long r = row0 + mf * 16 + l15;
        const int c = col0 + nf * 16 + lhi * 4;
        *(f32x4*)(C + r * LL + c) = acc[mf][nf];
      }

    // 4+5+6. retire loads (+ prev stores), cvt+write nbuf, barrier
    if (mt < 15) {
      // queue: S(t-1)<=16 | L(t)8 | S(t)16 -> vmcnt(16) retires S(t-1)+L
      asm volatile("s_waitcnt vmcnt(16)" ::: "memory");
      __builtin_amdgcn_sched_barrier(0);
      #pragma unroll
      for (int it = 0; it < 4; ++it) {
        const int idx = it * 512 + tid;
        const int row = idx >> 4, c8 = idx & 15;
        const u16x8 v = cvt8(nf4[it][0], nf4[it][1]);
        const int byte = (row * 256 + c8 * 16) ^ ((row & 7) << 4);
        *(u16x8*)((char*)nbuf + byte) = v;
      }
      asm volatile("s_waitcnt lgkmcnt(0)" ::: "memory");
      __builtin_amdgcn_sched_barrier(0);
      __builtin_amdgcn_s_barrier();
      __builtin_amdgcn_sched_barrier(0);
    }
  };

  #pragma unroll 1
  for (int mt2 = 0; mt2 < 8; ++mt2) {
    gen(2 * mt2, ldsA0, ldsA1);
    gen(2 * mt2 + 1, ldsA1, ldsA0);
  }
}

// ---------------------------------------------------------------
// launch
// ---------------------------------------------------------------
extern "C" void kernel_launch(void* const* d_in, const int* in_sizes, int n_in,
                              void* d_out, int out_size, void* d_ws, size_t ws_size,
                              hipStream_t stream) {
  const float* key = (const float*)d_in[0];  // (32, 2048, 128)
  const float* val = (const float*)d_in[1];  // (32, 256, 128)
  const float* wts = (const float*)d_in[2];  // (128, 64, 256)
  float* out = (float*)d_out;                // (32, 2048, 2048) fp32

  // workspace layout
  char* ws = (char*)d_ws;
  float* W2 = (float*)ws;                               // 128 KiB
  unsigned short* Tt = (unsigned short*)(ws + 131072);  // 1 MiB

  fold_w<<<128, 256, 0, stream>>>(wts, W2);
  compute_t<<<dim3(16, NB), 128, 0, stream>>>(W2, val, Tt);
  gemm_q<<<8 * NB, 512, 0, stream>>>(key, Tt, out);
}

// Round 16
// 153.884 us; speedup vs baseline: 1.1194x; 1.0260x over previous
//
#include <hip/hip_runtime.h>
#include <hip/hip_bf16.h>

#define KD 128   // KEY_DIM
#define VD 64    // VALUE_DIM
#define NA 256   // N_ACTIONS
#define NB 32    // B
#define LL 2048  // L

typedef __attribute__((ext_vector_type(8))) short bf16x8;
typedef __attribute__((ext_vector_type(4))) float f32x4;
typedef __attribute__((ext_vector_type(8))) unsigned short u16x8;
typedef __attribute__((ext_vector_type(4))) unsigned short u16x4;

static __device__ __forceinline__ unsigned short f2bf(float x) {
  __hip_bfloat16 h = __float2bfloat16(x);
  unsigned short u;
  __builtin_memcpy(&u, &h, 2);
  return u;
}

static __device__ __forceinline__ void stage16(const void* gsrc, void* ldst) {
  __builtin_amdgcn_global_load_lds(
      (const __attribute__((address_space(1))) void*)gsrc,
      (__attribute__((address_space(3))) void*)ldst, 16, 0, 0);
}

// ---------------------------------------------------------------
// K1: W2[n][a] = sum_k W[n][k][a]   (128 x 256 fp32)
// ---------------------------------------------------------------
__global__ __launch_bounds__(256) void fold_w(const float* __restrict__ W,
                                              float* __restrict__ W2) {
  const int idx = blockIdx.x * 256 + threadIdx.x;   // n*256 + a
  const int n = idx >> 8, a = idx & 255;
  const float* p = W + (long)n * (VD * NA) + a;
  float s = 0.f;
  #pragma unroll
  for (int k = 0; k < VD; ++k) s += p[k * NA];
  W2[idx] = s;
}

// ---------------------------------------------------------------
// K2: Tt[b][d][n] = sum_a W2[n][a] * V[b][a][d]   (bf16 out, transposed)
// ---------------------------------------------------------------
__global__ __launch_bounds__(128) void compute_t(const float* __restrict__ W2,
                                                 const float* __restrict__ V,
                                                 unsigned short* __restrict__ Tt) {
  const int n = threadIdx.x;
  const int d0 = blockIdx.x * 8;
  const int b = blockIdx.y;
  const float* vb = V + (long)b * NA * KD + d0;
  const float* w2p = W2 + n * NA;
  float acc[8] = {0.f, 0.f, 0.f, 0.f, 0.f, 0.f, 0.f, 0.f};
  for (int a = 0; a < NA; a += 4) {
    const float4 w = *(const float4*)(w2p + a);
    const float wq[4] = {w.x, w.y, w.z, w.w};
    #pragma unroll
    for (int q = 0; q < 4; ++q) {
      const float* vr = vb + (long)(a + q) * KD;
      #pragma unroll
      for (int j = 0; j < 8; ++j) acc[j] += wq[q] * vr[j];
    }
  }
  #pragma unroll
  for (int j = 0; j < 8; ++j)
    Tt[((long)b * KD + d0 + j) * KD + n] = f2bf(acc[j]);
}

// ---------------------------------------------------------------
// K3: key fp32 -> bf16, 8 elements/thread
// ---------------------------------------------------------------
__global__ __launch_bounds__(256) void cvt_key(const float* __restrict__ in,
                                               unsigned short* __restrict__ out) {
  const long i = ((long)blockIdx.x * 256 + threadIdx.x) * 8;
  const float4 f0 = *(const float4*)(in + i);
  const float4 f1 = *(const float4*)(in + i + 4);
  u16x8 r;
  r[0] = f2bf(f0.x); r[1] = f2bf(f0.y); r[2] = f2bf(f0.z); r[3] = f2bf(f0.w);
  r[4] = f2bf(f1.x); r[5] = f2bf(f1.y); r[6] = f2bf(f1.z); r[7] = f2bf(f1.w);
  *(u16x8*)(out + i) = r;
}

// ---------------------------------------------------------------
// K4: FUSED q GEMM, BM=256 x BN=128 per gen, 8 gens (HALF the sync
// events of round 13). Block (b, nt of 16), 512 blocks, 512 threads
// (8 waves, 2M x 4N -> wave tile 128 x 32). LDS = B panel 32 KB +
// A dbuf 2x64 KB = 160 KB (full CU).
// Prologue: stage Tt[b] (32 KB -> ldsA1) + keyB chunk rows
//   [nt*128,+128) (32 KB -> ldsB); panel = chunk @ Tt^T in regs
//   (pacc[8], 32 MFMA/wave); issue A(0); ds_write panel -> ldsB.
// Main loop (validated round-10/13 schedule, constants re-derived):
//   per gen: stage A(t+1) 64 KB (8 loads) -> compute 256x128 ->
//   16 stores -> vmcnt(16) [queue S(t-1)16|L8|S(t)16: retires
//   S(t-1)+L, keeps S(t) in flight] -> s_barrier.
// ---------------------------------------------------------------
__global__ __launch_bounds__(512, 2) void gemm_q(const unsigned short* __restrict__ A,
                                                 const unsigned short* __restrict__ Tt,
                                                 float* __restrict__ C) {
  __shared__ unsigned short ldsB[16384];   // 32 KB: chunk, then B panel
  __shared__ unsigned short ldsA0[32768];  // 64 KB: A ping
  __shared__ unsigned short ldsA1[32768];  // 64 KB: Tt (prologue), then A pong

  // 512 blocks: xcd = bid % 8 owns 64 logical = 4 whole batches
  const int lg = (blockIdx.x & 7) * 64 + (blockIdx.x >> 3);
  const int nt = lg & 15;
  const int b = lg >> 4;

  const int tid = threadIdx.x;
  const int lane = tid & 63, w = tid >> 6;     // 8 waves
  const int l15 = lane & 15, lhi = lane >> 4;
  const int wrM = w >> 2;                      // 0..1 : 128-row half (main loop)
  const int wcN = w & 3;                       // 0..3 : 32-col block (main loop)

  const unsigned short* gAb = A + (long)b * LL * KD;            // keyB[b]
  const unsigned short* gT = Tt + (long)b * KD * KD;            // Tt[b]
  const unsigned short* gChunk = gAb + (long)nt * 128 * KD;     // B-source rows

  // ---- prologue 1: stage Tt (32 KB -> ldsA1) + chunk (32 KB -> ldsB) ----
  #pragma unroll
  for (int i = 0; i < 4; ++i) {
    const int addr = i * 8192 + tid * 16;
    const int row = addr >> 8;
    const int src = addr ^ ((row & 7) << 4);
    stage16((const char*)gT + src, (char*)ldsA1 + addr);
    stage16((const char*)gChunk + src, (char*)ldsB + addr);
  }
  asm volatile("s_waitcnt vmcnt(0)" ::: "memory");
  __builtin_amdgcn_s_barrier();
  __builtin_amdgcn_sched_barrier(0);

  // ---- prologue 2: panel = chunk (128x128) @ Tt^T (128x128) in regs ----
  // wave w owns chunk rows [w*16, +16): pacc[df 0..7].
  f32x4 pacc[8];
  #pragma unroll
  for (int j = 0; j < 8; ++j) pacc[j] = f32x4{0.f, 0.f, 0.f, 0.f};

  #pragma unroll
  for (int ks = 0; ks < 4; ++ks) {
    const int kb = (ks * 32 + lhi * 8) * 2;
    bf16x8 av, bv[8];
    {
      const int row = w * 16 + l15;                    // 0..127 in chunk
      const int byte = (row * 256 + kb) ^ ((row & 7) << 4);
      av = *(const bf16x8*)((const char*)ldsB + byte);
    }
    #pragma unroll
    for (int df = 0; df < 8; ++df) {
      const int row = df * 16 + l15;                   // Tt row = d
      const int byte = (row * 256 + kb) ^ ((row & 7) << 4);
      bv[df] = *(const bf16x8*)((const char*)ldsA1 + byte);
    }
    #pragma unroll
    for (int df = 0; df < 8; ++df)
      pacc[df] = __builtin_amdgcn_mfma_f32_16x16x32_bf16(bv[df], av,
                                                         pacc[df], 0, 0, 0);
  }
  asm volatile("s_waitcnt lgkmcnt(0)" ::: "memory");
  __builtin_amdgcn_sched_barrier(0);
  __builtin_amdgcn_s_barrier();
  __builtin_amdgcn_sched_barrier(0);

  // ---- prologue 3: issue A(0) stage FIRST, then ds_write panel -> ldsB ----
  #pragma unroll
  for (int i = 0; i < 8; ++i) {
    const int addr = i * 8192 + tid * 16;    // 64 KB A tile (256 rows)
    const int row = addr >> 8;
    const int src = addr ^ ((row & 7) << 4);
    stage16((const char*)gAb + src, (char*)ldsA0 + addr);
  }
  __builtin_amdgcn_sched_barrier(0);
  // panel frag: lane&15 = chunk-row (within 16), lhi*4+reg = d col.
  #pragma unroll
  for (int df = 0; df < 8; ++df) {
    const int row = w * 16 + l15;                      // 0..127
    const int d = df * 16 + lhi * 4;
    u16x4 v;
    #pragma unroll
    for (int i = 0; i < 4; ++i) v[i] = f2bf(pacc[df][i]);
    const int byte = (row * 256 + d * 2) ^ ((row & 7) << 4);
    *(u16x4*)((char*)ldsB + byte) = v;
  }
  asm volatile("s_waitcnt vmcnt(0) lgkmcnt(0)" ::: "memory");
  __builtin_amdgcn_sched_barrier(0);
  __builtin_amdgcn_s_barrier();
  __builtin_amdgcn_sched_barrier(0);

  const int col0 = nt * 128 + wcN * 32;

  // ---- main loop: 8 gens of 256x128, round-13 schedule ----
  auto gen = [&](int mt, const unsigned short* abuf, unsigned short* nbuf) {
    // issue next-gen A(mt+1) stage FIRST (oldest in VM queue)
    if (mt < 7) {
      const char* gA = (const char*)(gAb + (long)(mt + 1) * 256 * KD);
      #pragma unroll
      for (int i = 0; i < 8; ++i) {
        const int addr = i * 8192 + tid * 16;
        const int row = addr >> 8;
        const int src = addr ^ ((row & 7) << 4);
        stage16(gA + src, (char*)nbuf + addr);
      }
    }
    __builtin_amdgcn_sched_barrier(0);

    // compute 256x128 from abuf + ldsB (wave tile 128x32)
    f32x4 acc[8][2];
    #pragma unroll
    for (int i = 0; i < 8; ++i)
      #pragma unroll
      for (int j = 0; j < 2; ++j) acc[i][j] = f32x4{0.f, 0.f, 0.f, 0.f};

    #pragma unroll
    for (int ks = 0; ks < 4; ++ks) {
      const int kb = (ks * 32 + lhi * 8) * 2;
      bf16x8 av[8], bv[2];
      #pragma unroll
      for (int mf = 0; mf < 8; ++mf) {
        const int row = wrM * 128 + mf * 16 + l15;     // 0..255
        const int byte = (row * 256 + kb) ^ ((row & 7) << 4);
        av[mf] = *(const bf16x8*)((const char*)abuf + byte);
      }
      #pragma unroll
      for (int nf = 0; nf < 2; ++nf) {
        const int row = wcN * 32 + nf * 16 + l15;      // 0..127
        const int byte = (row * 256 + kb) ^ ((row & 7) << 4);
        bv[nf] = *(const bf16x8*)((const char*)ldsB + byte);
      }
      // swapped operands: lane&15 = out row, (lane>>4)*4+reg = out col
      #pragma unroll
      for (int mf = 0; mf < 8; ++mf)
        #pragma unroll
        for (int nf = 0; nf < 2; ++nf)
          acc[mf][nf] = __builtin_amdgcn_mfma_f32_16x16x32_bf16(bv[nf], av[mf],
                                                                acc[mf][nf], 0, 0, 0);
    }

    // 16 cached dwordx4 stores (fire and forget)
    const long row0 = (long)b * LL + mt * 256 + wrM * 128;
    #pragma unroll
    for (int mf = 0; mf < 8; ++mf)
      #pragma unroll
      for (int nf = 0; nf < 2; ++nf) {
        const long r = row0 + mf * 16 + l15;
        const int c = col0 + nf * 16 + lhi * 4;
        *(f32x4*)(C + r * LL + c) = acc[mf][nf];
      }

    // end-of-gen: drain S(mt-1)+L(mt+1), keep S(mt) in flight
    if (mt < 7) {
      asm volatile("s_waitcnt vmcnt(16)" ::: "memory");
      __builtin_amdgcn_sched_barrier(0);
      __builtin_amdgcn_s_barrier();
      __builtin_amdgcn_sched_barrier(0);
    }
  };

  #pragma unroll 1
  for (int mt2 = 0; mt2 < 4; ++mt2) {
    gen(2 * mt2, ldsA0, ldsA1);
    gen(2 * mt2 + 1, ldsA1, ldsA0);
  }
}

// ---------------------------------------------------------------
// launch
// ---------------------------------------------------------------
extern "C" void kernel_launch(void* const* d_in, const int* in_sizes, int n_in,
                              void* d_out, int out_size, void* d_ws, size_t ws_size,
                              hipStream_t stream) {
  const float* key = (const float*)d_in[0];  // (32, 2048, 128)
  const float* val = (const float*)d_in[1];  // (32, 256, 128)
  const float* wts = (const float*)d_in[2];  // (128, 64, 256)
  float* out = (float*)d_out;                // (32, 2048, 2048) fp32

  // workspace layout
  char* ws = (char*)d_ws;
  float* W2 = (float*)ws;                                        // 128 KiB
  unsigned short* Tt = (unsigned short*)(ws + 131072);           // 1 MiB
  unsigned short* keyB = (unsigned short*)(ws + 131072 + 1048576);  // 16 MiB

  fold_w<<<128, 256, 0, stream>>>(wts, W2);
  cvt_key<<<4096, 256, 0, stream>>>(key, keyB);
  compute_t<<<dim3(16, NB), 128, 0, stream>>>(W2, val, Tt);
  gemm_q<<<16 * NB, 512, 0, stream>>>(keyB, Tt, out);
}